// Round 1
// baseline (7444.890 us; speedup 1.0000x reference)
//
#include <hip/hip_runtime.h>
#include <hip/hip_bf16.h>
#include <math.h>

#define S_LEN 2048
#define HID   2048
#define NH    32
#define NKV   8
#define HD    64

// ---------------------------------------------------------------------------
// fp32 tiled GEMM: C[M][N] = A[M][K] * B[K][N], all row-major.
// 64x64 block tile, BK=16, 256 threads, 4x4 micro-tile per thread.
// LDS stride 68 keeps float4 alignment (68*4 % 16 == 0) and <=2-way banks.
// ---------------------------------------------------------------------------
__global__ __launch_bounds__(256) void gemm_fp32(const float* __restrict__ A,
                                                 const float* __restrict__ B,
                                                 float* __restrict__ C,
                                                 int M, int N, int K) {
    __shared__ float As[16][68];
    __shared__ float Bs[16][68];

    const int tid = threadIdx.x;
    const int tx = tid & 15;        // col group 0..15
    const int ty = tid >> 4;        // row group 0..15
    const int bm = blockIdx.y * 64;
    const int bn = blockIdx.x * 64;

    float acc[4][4];
#pragma unroll
    for (int i = 0; i < 4; i++)
#pragma unroll
        for (int j = 0; j < 4; j++) acc[i][j] = 0.f;

    const int arow = tid >> 4;   // 0..15
    const int acol = tid & 15;   // k in tile
    const int brow = tid >> 6;   // 0..3
    const int bcol = tid & 63;

    for (int k0 = 0; k0 < K; k0 += 16) {
        // A tile: 64 rows x 16 k
#pragma unroll
        for (int i = 0; i < 4; i++)
            As[acol][arow + 16 * i] = A[(size_t)(bm + arow + 16 * i) * K + k0 + acol];
        // B tile: 16 k x 64 cols
#pragma unroll
        for (int i = 0; i < 4; i++)
            Bs[brow + 4 * i][bcol] = B[(size_t)(k0 + brow + 4 * i) * N + bn + bcol];
        __syncthreads();

#pragma unroll
        for (int kk = 0; kk < 16; kk++) {
            float4 av = *(const float4*)&As[kk][ty * 4];
            float4 bv = *(const float4*)&Bs[kk][tx * 4];
            acc[0][0] += av.x * bv.x; acc[0][1] += av.x * bv.y; acc[0][2] += av.x * bv.z; acc[0][3] += av.x * bv.w;
            acc[1][0] += av.y * bv.x; acc[1][1] += av.y * bv.y; acc[1][2] += av.y * bv.z; acc[1][3] += av.y * bv.w;
            acc[2][0] += av.z * bv.x; acc[2][1] += av.z * bv.y; acc[2][2] += av.z * bv.z; acc[2][3] += av.z * bv.w;
            acc[3][0] += av.w * bv.x; acc[3][1] += av.w * bv.y; acc[3][2] += av.w * bv.z; acc[3][3] += av.w * bv.w;
        }
        __syncthreads();
    }

#pragma unroll
    for (int i = 0; i < 4; i++) {
        float4 cv = make_float4(acc[i][0], acc[i][1], acc[i][2], acc[i][3]);
        *(float4*)&C[(size_t)(bm + ty * 4 + i) * N + bn + tx * 4] = cv;
    }
}

// ---------------------------------------------------------------------------
// RoPE applied in-place to Q (S x NH*HD) and K (S x NKV*HD).
// One thread per (pos, head, pair j). j in 0..31 pairs (d, d+32).
//   q'[j]    = q[j]*cos(s*f_j) - q[j+32]*sin(s*f_j)
//   q'[j+32] = q[j+32]*cos(s*f_j) + q[j]*sin(s*f_j)
// f_j = 10000^(-j/32) = exp(-j * ln(10000)/32)
// ---------------------------------------------------------------------------
__global__ __launch_bounds__(256) void rope_kernel(float* __restrict__ Q,
                                                   float* __restrict__ Kp) {
    const int PPR_Q = NH * 32;                 // 1024 pairs per row in Q
    const int PPR_K = NKV * 32;                // 256 pairs per row in K
    const int PPR = PPR_Q + PPR_K;             // 1280
    int idx = blockIdx.x * blockDim.x + threadIdx.x;
    int s = idx / PPR;
    int r = idx - s * PPR;
    if (s >= S_LEN) return;

    float* ptr;
    int j;
    if (r < PPR_Q) {
        int head = r >> 5;
        j = r & 31;
        ptr = Q + (size_t)s * (NH * HD) + head * HD + j;
    } else {
        int r2 = r - PPR_Q;
        int head = r2 >> 5;
        j = r2 & 31;
        ptr = Kp + (size_t)s * (NKV * HD) + head * HD + j;
    }
    const float LN1E4_OVER_32 = 0.2878231366242596f; // ln(10000)/32
    float inv = expf(-(float)j * LN1E4_OVER_32);
    float ang = (float)s * inv;
    float c = cosf(ang), sn = sinf(ang);
    float x1 = ptr[0], x2 = ptr[32];
    ptr[0]  = x1 * c - x2 * sn;
    ptr[32] = x2 * c + x1 * sn;
}

// ---------------------------------------------------------------------------
// Causal GQA attention, one wave per (head, query row). Online softmax.
// Q pre-scaled by 1/sqrt(64) at load. Output may alias Q (each block reads
// exactly the 64 floats it later overwrites, no cross-block overlap).
// grid: (S/4, NH); block: 256 (4 waves, one row each).
// ---------------------------------------------------------------------------
__global__ __launch_bounds__(256) void attn_kernel(const float* __restrict__ Q,
                                                   const float* __restrict__ K,
                                                   const float* __restrict__ V,
                                                   float* __restrict__ O) {
    const int w = threadIdx.x >> 6;
    const int lane = threadIdx.x & 63;
    const int q = blockIdx.x * 4 + w;
    const int h = blockIdx.y;
    const int kvh = h >> 2;            // groups = NH/NKV = 4

    const float* qrow = Q + (size_t)q * (NH * HD) + h * HD;
    float qreg[HD];
#pragma unroll
    for (int d4 = 0; d4 < 16; d4++) {
        float4 qv = *(const float4*)&qrow[d4 * 4];
        qreg[d4 * 4 + 0] = qv.x * 0.125f;
        qreg[d4 * 4 + 1] = qv.y * 0.125f;
        qreg[d4 * 4 + 2] = qv.z * 0.125f;
        qreg[d4 * 4 + 3] = qv.w * 0.125f;
    }

    float m = -INFINITY;
    float l = 0.f;
    float acc[4] = {0.f, 0.f, 0.f, 0.f};   // O[lane] split 4 ways for ILP

    const int nk = q + 1;
    for (int base = 0; base < nk; base += 64) {
        const int k = base + lane;
        float s = -INFINITY;
        if (k < nk) {
            const float* krow = K + (size_t)k * (NKV * HD) + kvh * HD;
            const float4* k4 = (const float4*)krow;
            float d0 = 0.f, d1 = 0.f, d2 = 0.f, d3 = 0.f;
#pragma unroll
            for (int d4 = 0; d4 < 16; d4 += 4) {
                float4 a = k4[d4 + 0];
                d0 += qreg[(d4 + 0) * 4 + 0] * a.x + qreg[(d4 + 0) * 4 + 1] * a.y +
                      qreg[(d4 + 0) * 4 + 2] * a.z + qreg[(d4 + 0) * 4 + 3] * a.w;
                float4 b = k4[d4 + 1];
                d1 += qreg[(d4 + 1) * 4 + 0] * b.x + qreg[(d4 + 1) * 4 + 1] * b.y +
                      qreg[(d4 + 1) * 4 + 2] * b.z + qreg[(d4 + 1) * 4 + 3] * b.w;
                float4 c = k4[d4 + 2];
                d2 += qreg[(d4 + 2) * 4 + 0] * c.x + qreg[(d4 + 2) * 4 + 1] * c.y +
                      qreg[(d4 + 2) * 4 + 2] * c.z + qreg[(d4 + 2) * 4 + 3] * c.w;
                float4 d = k4[d4 + 3];
                d3 += qreg[(d4 + 3) * 4 + 0] * d.x + qreg[(d4 + 3) * 4 + 1] * d.y +
                      qreg[(d4 + 3) * 4 + 2] * d.z + qreg[(d4 + 3) * 4 + 3] * d.w;
            }
            s = (d0 + d1) + (d2 + d3);
        }
        // wave max
        float cm = s;
#pragma unroll
        for (int off = 32; off; off >>= 1) cm = fmaxf(cm, __shfl_xor(cm, off));
        const float mnew = fmaxf(m, cm);
        const float p = expf(s - mnew);          // s=-inf -> 0
        const float alpha = expf(m - mnew);      // m=-inf first iter -> 0
        // wave sum of p
        float ps = p;
#pragma unroll
        for (int off = 32; off; off >>= 1) ps += __shfl_xor(ps, off);
        l = l * alpha + ps;
#pragma unroll
        for (int i = 0; i < 4; i++) acc[i] *= alpha;

        const float* vbase = V + (size_t)base * (NKV * HD) + kvh * HD + lane;
#pragma unroll
        for (int j = 0; j < 64; j++) {
            if (base + j < nk) {                  // wave-uniform branch
                float pj = __shfl(p, j);
                acc[j & 3] += pj * vbase[(size_t)j * (NKV * HD)];
            }
        }
        m = mnew;
    }

    O[(size_t)q * (NH * HD) + h * HD + lane] = ((acc[0] + acc[1]) + (acc[2] + acc[3])) / l;
}

// ---------------------------------------------------------------------------
// Launch
// ---------------------------------------------------------------------------
extern "C" void kernel_launch(void* const* d_in, const int* in_sizes, int n_in,
                              void* d_out, int out_size, void* d_ws, size_t ws_size,
                              hipStream_t stream) {
    const float* hidden = (const float*)d_in[0];   // S x HID
    const float* Wq = (const float*)d_in[1];       // HID x NH*HD
    const float* Wk = (const float*)d_in[2];       // HID x NKV*HD
    const float* Wv = (const float*)d_in[3];       // HID x NKV*HD
    const float* Wo = (const float*)d_in[4];       // NH*HD x HID
    // d_in[5] = attention_mask (causal; implemented structurally)
    float* out = (float*)d_out;

    char* ws = (char*)d_ws;
    float* Qb = (float*)ws;                                      // 2048*2048 f32 = 16 MB
    float* Kb = (float*)(ws + (size_t)S_LEN * HID * 4);          // 2048*512  f32 = 4 MB
    float* Vb = (float*)(ws + (size_t)S_LEN * HID * 4 + (size_t)S_LEN * NKV * HD * 4);
    float* Ob = Qb;  // attention output aliases Q (safe: block reads its 64 floats first)

    dim3 blk(256);

    // QKV projections
    gemm_fp32<<<dim3(HID / 64, S_LEN / 64), blk, 0, stream>>>(hidden, Wq, Qb, S_LEN, NH * HD, HID);
    gemm_fp32<<<dim3((NKV * HD) / 64, S_LEN / 64), blk, 0, stream>>>(hidden, Wk, Kb, S_LEN, NKV * HD, HID);
    gemm_fp32<<<dim3((NKV * HD) / 64, S_LEN / 64), blk, 0, stream>>>(hidden, Wv, Vb, S_LEN, NKV * HD, HID);

    // RoPE on Q and K
    {
        int total = S_LEN * (NH * 32 + NKV * 32);
        rope_kernel<<<(total + 255) / 256, blk, 0, stream>>>(Qb, Kb);
    }

    // Attention
    attn_kernel<<<dim3(S_LEN / 4, NH), blk, 0, stream>>>(Qb, Kb, Vb, Ob);

    // Output projection
    gemm_fp32<<<dim3(HID / 64, S_LEN / 64), blk, 0, stream>>>(Ob, Wo, out, S_LEN, HID, HID);
}

// Round 2
// 1271.453 us; speedup vs baseline: 5.8554x; 5.8554x over previous
//
#include <hip/hip_runtime.h>
#include <hip/hip_bf16.h>
#include <math.h>

#define S_LEN 2048
#define HID   2048
#define NH    32
#define NKV   8
#define HD    64
#define KVW   (NKV * HD)   // 512

typedef __attribute__((ext_vector_type(8))) short bf16x8;
typedef __attribute__((ext_vector_type(4))) float f32x4;

// round-to-nearest(-half-up) f32 -> bf16
__device__ __forceinline__ short f2bf(float f) {
    return (short)((__builtin_bit_cast(unsigned, f) + 0x8000u) >> 16);
}
__device__ __forceinline__ unsigned pack2bf(float a, float b) {
    unsigned ua = __builtin_bit_cast(unsigned, a) + 0x8000u;
    unsigned ub = __builtin_bit_cast(unsigned, b) + 0x8000u;
    return (ua >> 16) | (ub & 0xFFFF0000u);
}
__device__ __forceinline__ bf16x8 cvt_frag(float4 a, float4 b) {
    union { unsigned u[4]; bf16x8 v; } r;
    r.u[0] = pack2bf(a.x, a.y);
    r.u[1] = pack2bf(a.z, a.w);
    r.u[2] = pack2bf(b.x, b.y);
    r.u[3] = pack2bf(b.z, b.w);
    return r.v;
}

// ---------------------------------------------------------------------------
// fp32 tiled GEMM: C[M][N] = A[M][K] * B[K][N], row-major.
// TROUT=true writes C^T (Ct[N][M]) via scalar stores (used for V -> Vt).
// ---------------------------------------------------------------------------
template <bool TROUT>
__global__ __launch_bounds__(256) void gemm_fp32(const float* __restrict__ A,
                                                 const float* __restrict__ B,
                                                 float* __restrict__ C,
                                                 int M, int N, int K) {
    __shared__ float As[16][68];
    __shared__ float Bs[16][68];

    const int tid = threadIdx.x;
    const int tx = tid & 15;
    const int ty = tid >> 4;
    const int bm = blockIdx.y * 64;
    const int bn = blockIdx.x * 64;

    float acc[4][4];
#pragma unroll
    for (int i = 0; i < 4; i++)
#pragma unroll
        for (int j = 0; j < 4; j++) acc[i][j] = 0.f;

    const int arow = tid >> 4;
    const int acol = tid & 15;
    const int brow = tid >> 6;
    const int bcol = tid & 63;

    for (int k0 = 0; k0 < K; k0 += 16) {
#pragma unroll
        for (int i = 0; i < 4; i++)
            As[acol][arow + 16 * i] = A[(size_t)(bm + arow + 16 * i) * K + k0 + acol];
#pragma unroll
        for (int i = 0; i < 4; i++)
            Bs[brow + 4 * i][bcol] = B[(size_t)(k0 + brow + 4 * i) * N + bn + bcol];
        __syncthreads();

#pragma unroll
        for (int kk = 0; kk < 16; kk++) {
            float4 av = *(const float4*)&As[kk][ty * 4];
            float4 bv = *(const float4*)&Bs[kk][tx * 4];
            acc[0][0] += av.x * bv.x; acc[0][1] += av.x * bv.y; acc[0][2] += av.x * bv.z; acc[0][3] += av.x * bv.w;
            acc[1][0] += av.y * bv.x; acc[1][1] += av.y * bv.y; acc[1][2] += av.y * bv.z; acc[1][3] += av.y * bv.w;
            acc[2][0] += av.z * bv.x; acc[2][1] += av.z * bv.y; acc[2][2] += av.z * bv.z; acc[2][3] += av.z * bv.w;
            acc[3][0] += av.w * bv.x; acc[3][1] += av.w * bv.y; acc[3][2] += av.w * bv.z; acc[3][3] += av.w * bv.w;
        }
        __syncthreads();
    }

    if (TROUT) {
#pragma unroll
        for (int i = 0; i < 4; i++)
#pragma unroll
            for (int j = 0; j < 4; j++)
                C[(size_t)(bn + tx * 4 + j) * M + bm + ty * 4 + i] = acc[i][j];
    } else {
#pragma unroll
        for (int i = 0; i < 4; i++) {
            float4 cv = make_float4(acc[i][0], acc[i][1], acc[i][2], acc[i][3]);
            *(float4*)&C[(size_t)(bm + ty * 4 + i) * N + bn + tx * 4] = cv;
        }
    }
}

// ---------------------------------------------------------------------------
// RoPE in-place on Q (S x 2048) and K (S x 512), fp32.
// ---------------------------------------------------------------------------
__global__ __launch_bounds__(256) void rope_kernel(float* __restrict__ Q,
                                                   float* __restrict__ Kp) {
    const int PPR_Q = NH * 32;
    const int PPR_K = NKV * 32;
    const int PPR = PPR_Q + PPR_K;
    int idx = blockIdx.x * blockDim.x + threadIdx.x;
    int s = idx / PPR;
    int r = idx - s * PPR;
    if (s >= S_LEN) return;

    float* ptr;
    int j;
    if (r < PPR_Q) {
        int head = r >> 5;
        j = r & 31;
        ptr = Q + (size_t)s * (NH * HD) + head * HD + j;
    } else {
        int r2 = r - PPR_Q;
        int head = r2 >> 5;
        j = r2 & 31;
        ptr = Kp + (size_t)s * KVW + head * HD + j;
    }
    const float LN1E4_OVER_32 = 0.2878231366242596f;
    float inv = expf(-(float)j * LN1E4_OVER_32);
    float ang = (float)s * inv;
    float c = cosf(ang), sn = sinf(ang);
    float x1 = ptr[0], x2 = ptr[32];
    ptr[0]  = x1 * c - x2 * sn;
    ptr[32] = x2 * c + x1 * sn;
}

// ---------------------------------------------------------------------------
// Flash attention, bf16 MFMA 16x16x32.
// grid (S/64, NH), block 256 (4 waves). Wave w owns 16 q rows.
// Q,K fp32 (RoPE'd); Vt fp32 transposed [d_total=512][S]. O aliases Q safely.
// Fragment layouts (gfx950, measured m89/m91/m120):
//   A[m=lane&15][k=quad*8+j], B[n=lane&15][k=quad*8+j],
//   C/D: col=lane&15, row=quad*4+reg.
// ---------------------------------------------------------------------------
__global__ __launch_bounds__(256) void attn_mfma(const float* __restrict__ Q,
                                                 const float* __restrict__ K,
                                                 const float* __restrict__ Vt,
                                                 float* __restrict__ O) {
    __shared__ short P_lds[4][16][72];   // per-wave P tile, stride 72 bf16

    const int w    = threadIdx.x >> 6;
    const int lane = threadIdx.x & 63;
    const int qd   = lane >> 4;          // quad 0..3
    const int r    = lane & 15;
    const int qb   = (S_LEN / 64 - 1) - blockIdx.x;   // heavy blocks first
    const int h    = blockIdx.y;
    const int kvh  = h >> 2;             // GQA group of 4
    const int q0w  = qb * 64 + w * 16;

    // Q A-fragments (2 k-steps over d), scaled by 1/sqrt(64)
    const float* qbase = Q + (size_t)(q0w + r) * (NH * HD) + h * HD;
    bf16x8 qfrag[2];
#pragma unroll
    for (int c = 0; c < 2; c++) {
        float4 a = *(const float4*)(qbase + c * 32 + qd * 8);
        float4 b = *(const float4*)(qbase + c * 32 + qd * 8 + 4);
        a.x *= 0.125f; a.y *= 0.125f; a.z *= 0.125f; a.w *= 0.125f;
        b.x *= 0.125f; b.y *= 0.125f; b.z *= 0.125f; b.w *= 0.125f;
        qfrag[c] = cvt_frag(a, b);
    }

    f32x4 oacc[4];
    float m[4], l[4];
#pragma unroll
    for (int i = 0; i < 4; i++) {
        oacc[i][0] = 0.f; oacc[i][1] = 0.f; oacc[i][2] = 0.f; oacc[i][3] = 0.f;
        m[i] = -1e30f; l[i] = 0.f;
    }

    for (int kt = 0; kt <= qb; kt++) {
        // ---- S = Q K^T for 16 q x 64 keys ----
        f32x4 s[4];
#pragma unroll
        for (int nt = 0; nt < 4; nt++) { s[nt][0]=0.f; s[nt][1]=0.f; s[nt][2]=0.f; s[nt][3]=0.f; }

        const float* kbase = K + (size_t)(kt * 64) * KVW + kvh * HD;
#pragma unroll
        for (int nt = 0; nt < 4; nt++) {
            const float* krow = kbase + (size_t)(nt * 16 + r) * KVW;
#pragma unroll
            for (int c = 0; c < 2; c++) {
                float4 a = *(const float4*)(krow + c * 32 + qd * 8);
                float4 b = *(const float4*)(krow + c * 32 + qd * 8 + 4);
                bf16x8 kf = cvt_frag(a, b);
                s[nt] = __builtin_amdgcn_mfma_f32_16x16x32_bf16(qfrag[c], kf, s[nt], 0, 0, 0);
            }
        }

        // ---- causal mask on diagonal tile ----
        if (kt == qb) {
#pragma unroll
            for (int nt = 0; nt < 4; nt++) {
                int key_local = nt * 16 + r;
#pragma unroll
                for (int reg = 0; reg < 4; reg++) {
                    int q_local = w * 16 + qd * 4 + reg;
                    if (key_local > q_local) s[nt][reg] = -1e30f;
                }
            }
        }

        // ---- online softmax (rows = qd*4+reg, reduce across 16 lanes r) ----
        float rmax[4];
#pragma unroll
        for (int reg = 0; reg < 4; reg++) {
            rmax[reg] = fmaxf(fmaxf(s[0][reg], s[1][reg]), fmaxf(s[2][reg], s[3][reg]));
#pragma unroll
            for (int off = 8; off >= 1; off >>= 1)
                rmax[reg] = fmaxf(rmax[reg], __shfl_xor(rmax[reg], off));
        }
        float alpha[4], psum[4];
#pragma unroll
        for (int reg = 0; reg < 4; reg++) {
            float mnew = fmaxf(m[reg], rmax[reg]);
            alpha[reg] = __expf(m[reg] - mnew);
            m[reg] = mnew;
            psum[reg] = 0.f;
        }
#pragma unroll
        for (int nt = 0; nt < 4; nt++) {
#pragma unroll
            for (int reg = 0; reg < 4; reg++) {
                float p = __expf(s[nt][reg] - m[reg]);
                psum[reg] += p;
                P_lds[w][qd * 4 + reg][nt * 16 + r] = f2bf(p);
            }
        }
#pragma unroll
        for (int reg = 0; reg < 4; reg++) {
#pragma unroll
            for (int off = 8; off >= 1; off >>= 1)
                psum[reg] += __shfl_xor(psum[reg], off);
            l[reg] = l[reg] * alpha[reg] + psum[reg];
        }
#pragma unroll
        for (int nt = 0; nt < 4; nt++)
#pragma unroll
            for (int reg = 0; reg < 4; reg++) oacc[nt][reg] *= alpha[reg];

        __syncthreads();   // P write -> P read (also keeps waves in lockstep for L1 reuse)

        // ---- O += P V  (A = P from LDS, B = Vt rows from global) ----
#pragma unroll
        for (int c = 0; c < 2; c++) {
            bf16x8 pf = *(const bf16x8*)&P_lds[w][r][c * 32 + qd * 8];
#pragma unroll
            for (int ntd = 0; ntd < 4; ntd++) {
                const float* vrow = Vt + (size_t)(kvh * HD + ntd * 16 + r) * S_LEN
                                       + kt * 64 + c * 32 + qd * 8;
                float4 a = *(const float4*)(vrow);
                float4 b = *(const float4*)(vrow + 4);
                oacc[ntd] = __builtin_amdgcn_mfma_f32_16x16x32_bf16(pf, cvt_frag(a, b), oacc[ntd], 0, 0, 0);
            }
        }
        __syncthreads();   // protect P_lds against next-iteration overwrite
    }

    // ---- epilogue: O / l, store ----
    float rl[4];
#pragma unroll
    for (int reg = 0; reg < 4; reg++) rl[reg] = 1.f / l[reg];
#pragma unroll
    for (int ntd = 0; ntd < 4; ntd++)
#pragma unroll
        for (int reg = 0; reg < 4; reg++)
            O[(size_t)(q0w + qd * 4 + reg) * (NH * HD) + h * HD + ntd * 16 + r] =
                oacc[ntd][reg] * rl[reg];
}

// ---------------------------------------------------------------------------
// Launch
// ---------------------------------------------------------------------------
extern "C" void kernel_launch(void* const* d_in, const int* in_sizes, int n_in,
                              void* d_out, int out_size, void* d_ws, size_t ws_size,
                              hipStream_t stream) {
    const float* hidden = (const float*)d_in[0];
    const float* Wq = (const float*)d_in[1];
    const float* Wk = (const float*)d_in[2];
    const float* Wv = (const float*)d_in[3];
    const float* Wo = (const float*)d_in[4];
    float* out = (float*)d_out;

    char* ws = (char*)d_ws;
    float* Qb = (float*)ws;                                       // 16 MB
    float* Kb = (float*)(ws + (size_t)S_LEN * HID * 4);           // 4 MB
    float* Vt = (float*)(ws + (size_t)S_LEN * HID * 4 + (size_t)S_LEN * KVW * 4); // 4 MB, [512][2048]
    float* Ob = Qb;   // attention output aliases Q (block reads its rows first)

    dim3 blk(256);

    gemm_fp32<false><<<dim3(HID / 64, S_LEN / 64), blk, 0, stream>>>(hidden, Wq, Qb, S_LEN, NH * HD, HID);
    gemm_fp32<false><<<dim3(KVW / 64, S_LEN / 64), blk, 0, stream>>>(hidden, Wk, Kb, S_LEN, KVW, HID);
    gemm_fp32<true ><<<dim3(KVW / 64, S_LEN / 64), blk, 0, stream>>>(hidden, Wv, Vt, S_LEN, KVW, HID);

    {
        int total = S_LEN * (NH * 32 + NKV * 32);
        rope_kernel<<<(total + 255) / 256, blk, 0, stream>>>(Qb, Kb);
    }

    attn_mfma<<<dim3(S_LEN / 64, NH), blk, 0, stream>>>(Qb, Kb, Vt, Ob);

    gemm_fp32<false><<<dim3(HID / 64, S_LEN / 64), blk, 0, stream>>>(Ob, Wo, out, S_LEN, HID, HID);
}

// Round 3
// 484.943 us; speedup vs baseline: 15.3521x; 2.6219x over previous
//
#include <hip/hip_runtime.h>
#include <hip/hip_bf16.h>
#include <math.h>

#define S_LEN 2048
#define HID   2048
#define NH    32
#define NKV   8
#define HD    64
#define KVW   (NKV * HD)   // 512

typedef __attribute__((ext_vector_type(8))) short bf16x8;
typedef __attribute__((ext_vector_type(4))) float f32x4;
typedef unsigned short u16;

__device__ __forceinline__ u16 f2bf(float f) {
    return (u16)((__builtin_bit_cast(unsigned, f) + 0x8000u) >> 16);
}
__device__ __forceinline__ unsigned pack2bf(float a, float b) {
    unsigned ua = __builtin_bit_cast(unsigned, a) + 0x8000u;
    unsigned ub = __builtin_bit_cast(unsigned, b) + 0x8000u;
    return (ua >> 16) | (ub & 0xFFFF0000u);
}
__device__ __forceinline__ bf16x8 cvt_frag(float4 a, float4 b) {
    union { unsigned u[4]; bf16x8 v; } r;
    r.u[0] = pack2bf(a.x, a.y);
    r.u[1] = pack2bf(a.z, a.w);
    r.u[2] = pack2bf(b.x, b.y);
    r.u[3] = pack2bf(b.z, b.w);
    return r.v;
}

// ---------------------------------------------------------------------------
// Elementwise f32 -> bf16 (8 elems/thread).
// ---------------------------------------------------------------------------
__global__ __launch_bounds__(256) void cvt_bf16x8_kernel(const float* __restrict__ X,
                                                         u16* __restrict__ Y, int n8) {
    int i = blockIdx.x * 256 + threadIdx.x;
    if (i >= n8) return;
    const float4* p = (const float4*)(X + (size_t)i * 8);
    float4 a = p[0], b = p[1];
    uint4 o;
    o.x = pack2bf(a.x, a.y);
    o.y = pack2bf(a.z, a.w);
    o.z = pack2bf(b.x, b.y);
    o.w = pack2bf(b.z, b.w);
    *(uint4*)(Y + (size_t)i * 8) = o;
}

// ---------------------------------------------------------------------------
// Transpose + convert: X0/X1 fp32 [R][C] -> Y0/Y1 bf16 [C][R]. z picks pair.
// ---------------------------------------------------------------------------
__global__ __launch_bounds__(256) void transpose_cvt2(const float* __restrict__ X0,
                                                      u16* __restrict__ Y0,
                                                      const float* __restrict__ X1,
                                                      u16* __restrict__ Y1,
                                                      int R, int C) {
    const float* X = blockIdx.z ? X1 : X0;
    u16* Y = blockIdx.z ? Y1 : Y0;
    __shared__ float T[32][33];
    const int tx = threadIdx.x & 31, ty = threadIdx.x >> 5;
    const int c0 = blockIdx.x * 32, r0 = blockIdx.y * 32;
#pragma unroll
    for (int i = 0; i < 4; i++)
        T[ty + 8 * i][tx] = X[(size_t)(r0 + ty + 8 * i) * C + c0 + tx];
    __syncthreads();
#pragma unroll
    for (int i = 0; i < 4; i++)
        Y[(size_t)(c0 + ty + 8 * i) * R + r0 + tx] = f2bf(T[tx][ty + 8 * i]);
}

// ---------------------------------------------------------------------------
// bf16 MFMA GEMM: C[M][N] = A[M][K] * Bt[N][K]^T   (A, Bt bf16, both K-major)
// Block = 256 threads = 4 waves (2x2), wave tile = (WMT*16) x (WNT*16).
// BM = 32*WMT, BN = 32*WNT, BK = 32. global_load_lds width-16 staging (m97).
// TROUT=true writes bf16 C^T to Ct (used for V -> Vt); else fp32 C.
// Fragment layouts (measured m89/m91): A[m=lane&15][k=quad*8+j],
// B[n=lane&15][k=quad*8+j], C/D row(m)=quad*4+reg, col(n)=lane&15.
// ---------------------------------------------------------------------------
template <int WMT, int WNT, bool TROUT>
__global__ __launch_bounds__(256) void gemm_bf16(const u16* __restrict__ A,
                                                 const u16* __restrict__ Bt,
                                                 float* __restrict__ C,
                                                 u16* __restrict__ Ct,
                                                 int M, int N, int K) {
    constexpr int BM = 32 * WMT;
    constexpr int BN = 32 * WNT;
    __shared__ u16 As[BM * 32];
    __shared__ u16 Bs[BN * 32];

    const int t = threadIdx.x;
    const int w = t >> 6, lane = t & 63;
    const int qd = lane >> 4, r = lane & 15;
    const int wm = w >> 1, wn = w & 1;
    const int bm = blockIdx.y * BM, bn = blockIdx.x * BN;

    f32x4 acc[WMT][WNT];
#pragma unroll
    for (int i = 0; i < WMT; i++)
#pragma unroll
        for (int j = 0; j < WNT; j++) {
            acc[i][j][0] = 0.f; acc[i][j][1] = 0.f; acc[i][j][2] = 0.f; acc[i][j][3] = 0.f;
        }

    for (int k0 = 0; k0 < K; k0 += 32) {
        __syncthreads();   // previous iteration's reads done before overwrite
#pragma unroll
        for (int rd = 0; rd < BM / 64; rd++) {
            int c = rd * 256 + t;                       // 16B chunk id
            const u16* g = A + (size_t)(bm + (c >> 2)) * K + k0 + (c & 3) * 8;
            u16* l = As + (size_t)(rd * 256 + w * 64) * 8;   // wave-uniform base
            __builtin_amdgcn_global_load_lds((const __attribute__((address_space(1))) void*)g,
                                             (__attribute__((address_space(3))) void*)l, 16, 0, 0);
        }
#pragma unroll
        for (int rd = 0; rd < BN / 64; rd++) {
            int c = rd * 256 + t;
            const u16* g = Bt + (size_t)(bn + (c >> 2)) * K + k0 + (c & 3) * 8;
            u16* l = Bs + (size_t)(rd * 256 + w * 64) * 8;
            __builtin_amdgcn_global_load_lds((const __attribute__((address_space(1))) void*)g,
                                             (__attribute__((address_space(3))) void*)l, 16, 0, 0);
        }
        __syncthreads();   // staging visible

        bf16x8 af[WMT], bfr[WNT];
#pragma unroll
        for (int i = 0; i < WMT; i++)
            af[i] = *(const bf16x8*)&As[(wm * WMT * 16 + i * 16 + r) * 32 + qd * 8];
#pragma unroll
        for (int j = 0; j < WNT; j++)
            bfr[j] = *(const bf16x8*)&Bs[(wn * WNT * 16 + j * 16 + r) * 32 + qd * 8];
#pragma unroll
        for (int i = 0; i < WMT; i++)
#pragma unroll
            for (int j = 0; j < WNT; j++)
                acc[i][j] = __builtin_amdgcn_mfma_f32_16x16x32_bf16(af[i], bfr[j], acc[i][j], 0, 0, 0);
    }

    if (TROUT) {
#pragma unroll
        for (int i = 0; i < WMT; i++)
#pragma unroll
            for (int j = 0; j < WNT; j++)
#pragma unroll
                for (int reg = 0; reg < 4; reg++)
                    Ct[(size_t)(bn + wn * WNT * 16 + j * 16 + r) * M
                       + bm + wm * WMT * 16 + i * 16 + qd * 4 + reg] = f2bf(acc[i][j][reg]);
    } else {
#pragma unroll
        for (int i = 0; i < WMT; i++)
#pragma unroll
            for (int j = 0; j < WNT; j++)
#pragma unroll
                for (int reg = 0; reg < 4; reg++)
                    C[(size_t)(bm + wm * WMT * 16 + i * 16 + qd * 4 + reg) * N
                      + bn + wn * WNT * 16 + j * 16 + r] = acc[i][j][reg];
    }
}

// ---------------------------------------------------------------------------
// RoPE: Q fp32 in-place; K fp32 -> bf16 Kh (rotated).
// ---------------------------------------------------------------------------
__global__ __launch_bounds__(256) void rope_cvt(float* __restrict__ Q,
                                                const float* __restrict__ Kf,
                                                u16* __restrict__ Kh) {
    const int PPR_Q = NH * 32;
    const int PPR_K = NKV * 32;
    const int PPR = PPR_Q + PPR_K;
    int idx = blockIdx.x * blockDim.x + threadIdx.x;
    int s = idx / PPR;
    int r = idx - s * PPR;
    if (s >= S_LEN) return;

    const float LN1E4_OVER_32 = 0.2878231366242596f;  // ln(10000)/32
    if (r < PPR_Q) {
        int head = r >> 5;
        int j = r & 31;
        float* ptr = Q + (size_t)s * (NH * HD) + head * HD + j;
        float inv = expf(-(float)j * LN1E4_OVER_32);
        float ang = (float)s * inv;
        float c = cosf(ang), sn = sinf(ang);
        float x1 = ptr[0], x2 = ptr[32];
        ptr[0]  = x1 * c - x2 * sn;
        ptr[32] = x2 * c + x1 * sn;
    } else {
        int r2 = r - PPR_Q;
        int head = r2 >> 5;
        int j = r2 & 31;
        size_t off = (size_t)s * KVW + head * HD + j;
        float inv = expf(-(float)j * LN1E4_OVER_32);
        float ang = (float)s * inv;
        float c = cosf(ang), sn = sinf(ang);
        float x1 = Kf[off], x2 = Kf[off + 32];
        Kh[off]      = f2bf(x1 * c - x2 * sn);
        Kh[off + 32] = f2bf(x2 * c + x1 * sn);
    }
}

// ---------------------------------------------------------------------------
// Flash attention, bf16 MFMA 16x16x32, NO barriers (P_lds is per-wave;
// same-wave DS ops are ordered). Q fp32 (RoPE'd), K bf16 [S][512],
// Vt bf16 [512][S]. Output bf16 [S][2048] (A operand of out-proj).
// ---------------------------------------------------------------------------
__global__ __launch_bounds__(256) void attn_mfma(const float* __restrict__ Q,
                                                 const u16* __restrict__ K,
                                                 const u16* __restrict__ Vt,
                                                 u16* __restrict__ O) {
    __shared__ u16 P_lds[4][16][72];   // per-wave P tile

    const int w    = threadIdx.x >> 6;
    const int lane = threadIdx.x & 63;
    const int qd   = lane >> 4;
    const int r    = lane & 15;
    const int qb   = (S_LEN / 64 - 1) - blockIdx.x;   // heavy blocks first
    const int h    = blockIdx.y;
    const int kvh  = h >> 2;
    const int q0w  = qb * 64 + w * 16;

    const float* qbase = Q + (size_t)(q0w + r) * (NH * HD) + h * HD;
    bf16x8 qfrag[2];
#pragma unroll
    for (int c = 0; c < 2; c++) {
        float4 a = *(const float4*)(qbase + c * 32 + qd * 8);
        float4 b = *(const float4*)(qbase + c * 32 + qd * 8 + 4);
        a.x *= 0.125f; a.y *= 0.125f; a.z *= 0.125f; a.w *= 0.125f;
        b.x *= 0.125f; b.y *= 0.125f; b.z *= 0.125f; b.w *= 0.125f;
        qfrag[c] = cvt_frag(a, b);
    }

    f32x4 oacc[4];
    float m[4], l[4];
#pragma unroll
    for (int i = 0; i < 4; i++) {
        oacc[i][0] = 0.f; oacc[i][1] = 0.f; oacc[i][2] = 0.f; oacc[i][3] = 0.f;
        m[i] = -1e30f; l[i] = 0.f;
    }

    for (int kt = 0; kt <= qb; kt++) {
        // ---- S = Q K^T (16 q x 64 keys) ----
        f32x4 s[4];
#pragma unroll
        for (int nt = 0; nt < 4; nt++) { s[nt][0]=0.f; s[nt][1]=0.f; s[nt][2]=0.f; s[nt][3]=0.f; }

        const u16* kbase = K + (size_t)(kt * 64) * KVW + kvh * HD;
#pragma unroll
        for (int nt = 0; nt < 4; nt++) {
            const u16* krow = kbase + (size_t)(nt * 16 + r) * KVW;
#pragma unroll
            for (int c = 0; c < 2; c++) {
                bf16x8 kf = *(const bf16x8*)(krow + c * 32 + qd * 8);
                s[nt] = __builtin_amdgcn_mfma_f32_16x16x32_bf16(qfrag[c], kf, s[nt], 0, 0, 0);
            }
        }

        // ---- causal mask on diagonal tile ----
        if (kt == qb) {
#pragma unroll
            for (int nt = 0; nt < 4; nt++) {
                int key_local = nt * 16 + r;
#pragma unroll
                for (int reg = 0; reg < 4; reg++) {
                    int q_local = w * 16 + qd * 4 + reg;
                    if (key_local > q_local) s[nt][reg] = -1e30f;
                }
            }
        }

        // ---- online softmax (rows = qd*4+reg, reduce across 16 lanes r) ----
        float rmax[4];
#pragma unroll
        for (int reg = 0; reg < 4; reg++) {
            rmax[reg] = fmaxf(fmaxf(s[0][reg], s[1][reg]), fmaxf(s[2][reg], s[3][reg]));
#pragma unroll
            for (int off = 8; off >= 1; off >>= 1)
                rmax[reg] = fmaxf(rmax[reg], __shfl_xor(rmax[reg], off));
        }
        float alpha[4], psum[4];
#pragma unroll
        for (int reg = 0; reg < 4; reg++) {
            float mnew = fmaxf(m[reg], rmax[reg]);
            alpha[reg] = __expf(m[reg] - mnew);
            m[reg] = mnew;
            psum[reg] = 0.f;
        }
#pragma unroll
        for (int nt = 0; nt < 4; nt++) {
#pragma unroll
            for (int reg = 0; reg < 4; reg++) {
                float p = __expf(s[nt][reg] - m[reg]);
                psum[reg] += p;
                P_lds[w][qd * 4 + reg][nt * 16 + r] = f2bf(p);
            }
        }
#pragma unroll
        for (int reg = 0; reg < 4; reg++) {
#pragma unroll
            for (int off = 8; off >= 1; off >>= 1)
                psum[reg] += __shfl_xor(psum[reg], off);
            l[reg] = l[reg] * alpha[reg] + psum[reg];
        }
#pragma unroll
        for (int nt = 0; nt < 4; nt++)
#pragma unroll
            for (int reg = 0; reg < 4; reg++) oacc[nt][reg] *= alpha[reg];

        // ---- O += P V  (A = P from per-wave LDS, B = Vt rows) ----
#pragma unroll
        for (int c = 0; c < 2; c++) {
            bf16x8 pf = *(const bf16x8*)&P_lds[w][r][c * 32 + qd * 8];
#pragma unroll
            for (int ntd = 0; ntd < 4; ntd++) {
                const u16* vrow = Vt + (size_t)(kvh * HD + ntd * 16 + r) * S_LEN
                                     + kt * 64 + c * 32 + qd * 8;
                bf16x8 vf = *(const bf16x8*)vrow;
                oacc[ntd] = __builtin_amdgcn_mfma_f32_16x16x32_bf16(pf, vf, oacc[ntd], 0, 0, 0);
            }
        }
    }

    // ---- epilogue: O / l, store bf16 ----
    float rl[4];
#pragma unroll
    for (int reg = 0; reg < 4; reg++) rl[reg] = 1.f / l[reg];
#pragma unroll
    for (int ntd = 0; ntd < 4; ntd++)
#pragma unroll
        for (int reg = 0; reg < 4; reg++)
            O[(size_t)(q0w + qd * 4 + reg) * (NH * HD) + h * HD + ntd * 16 + r] =
                f2bf(oacc[ntd][reg] * rl[reg]);
}

// ---------------------------------------------------------------------------
// Launch
// ---------------------------------------------------------------------------
extern "C" void kernel_launch(void* const* d_in, const int* in_sizes, int n_in,
                              void* d_out, int out_size, void* d_ws, size_t ws_size,
                              hipStream_t stream) {
    const float* hidden = (const float*)d_in[0];
    const float* Wq = (const float*)d_in[1];
    const float* Wk = (const float*)d_in[2];
    const float* Wv = (const float*)d_in[3];
    const float* Wo = (const float*)d_in[4];
    float* out = (float*)d_out;

    char* ws = (char*)d_ws;
    const size_t MB = 1024 * 1024;
    u16*   Hh  = (u16*)(ws + 0 * MB);    // bf16 hidden        [2048][2048]  8 MB
    u16*   WqT = (u16*)(ws + 8 * MB);    // bf16 Wq^T          [2048][2048]  8 MB
    u16*   WoT = (u16*)(ws + 16 * MB);   // bf16 Wo^T          [2048][2048]  8 MB
    u16*   WkT = (u16*)(ws + 24 * MB);   // bf16 Wk^T          [512][2048]   2 MB
    u16*   WvT = (u16*)(ws + 26 * MB);   // bf16 Wv^T          [512][2048]   2 MB
    u16*   Vt  = (u16*)(ws + 28 * MB);   // bf16 V^T           [512][2048]   2 MB
    u16*   Kh  = (u16*)(ws + 30 * MB);   // bf16 K (RoPE'd)    [2048][512]   2 MB
    float* Qb  = (float*)(ws + 32 * MB); // fp32 Q (RoPE'd)    [2048][2048] 16 MB
    float* Kb  = (float*)(ws + 48 * MB); // fp32 K pre-RoPE    [2048][512]   4 MB
    u16*   Ob  = WqT;                    // attn out bf16, reuses WqT (dead after Qproj)

    dim3 blk(256);

    // dtype conversions / weight transposes
    cvt_bf16x8_kernel<<<(S_LEN * HID / 8 + 255) / 256, blk, 0, stream>>>(hidden, Hh, S_LEN * HID / 8);
    transpose_cvt2<<<dim3(HID / 32, HID / 32, 2), blk, 0, stream>>>(Wq, WqT, Wo, WoT, HID, HID);
    transpose_cvt2<<<dim3(KVW / 32, HID / 32, 2), blk, 0, stream>>>(Wk, WkT, Wv, WvT, HID, KVW);

    // projections (bf16 MFMA)
    gemm_bf16<4, 2, false><<<dim3(HID / 64, S_LEN / 128), blk, 0, stream>>>(Hh, WqT, Qb, nullptr, S_LEN, HID, HID);
    gemm_bf16<2, 2, false><<<dim3(KVW / 64, S_LEN / 64), blk, 0, stream>>>(Hh, WkT, Kb, nullptr, S_LEN, KVW, HID);
    gemm_bf16<2, 2, true ><<<dim3(KVW / 64, S_LEN / 64), blk, 0, stream>>>(Hh, WvT, nullptr, Vt, S_LEN, KVW, HID);

    // RoPE (Q fp32 in-place, K -> bf16)
    {
        int total = S_LEN * (NH * 32 + NKV * 32);
        rope_cvt<<<(total + 255) / 256, blk, 0, stream>>>(Qb, Kb, Kh);
    }

    // attention
    attn_mfma<<<dim3(S_LEN / 64, NH), blk, 0, stream>>>(Qb, Kh, Vt, Ob);

    // output projection
    gemm_bf16<4, 2, false><<<dim3(HID / 64, S_LEN / 128), blk, 0, stream>>>(Ob, WoT, out, nullptr, S_LEN, HID, HID);
}